// Round 8
// baseline (279.728 us; speedup 1.0000x reference)
//
#include <hip/hip_runtime.h>
#include <hip/hip_bf16.h>

// GRU policy: B=2048, T=512, V=4, E=64, H=128.
// R21 = R20 (244.6us dispatch, best) + KERNEL FUSION: gi_table computed
// in-block during setup (3 entries/thread x 64 FMA ~ 200cy, hidden under
// W_hh staging); gi_table_kernel + workspace deleted -> single launch.
// Targets the ~28us harness-vs-dispatch gap (2nd dispatch + graph gap).
// In-loop structure CONFIRMED AT FLOOR (R20): step 1146cy; MFMA 12/wave
// (2x replication forced by B/CU=8), trans 5/elem algebraic floor, tail
// packed, LDS ops non-binding (R19), overlap 0-for-7, 2blk/CU 4.2x worse
// (R17). Only cross-kernel overhead remained.
// Ledger: R14 bank-pad WIN; R15 DPP FAILED; R16 occupancy WIN; R17 2blk/CU
// FAILED 4.2x; R18 split-K FAILED; R19 gi-to-VGPR FAILED (+VALU 1:1);
// R20 reassembly WIN (-9.4%). Pre-commit: harness >=268us => ROOFLINE.
// Per wave/step: 12 MFMA, 4 ds_read_b128(h) + 2 b128 + 1 b64 (gi) + 1 u8
// + 1 ds_write_b32, 10 trans, ~40 VALU. 1 barrier/step. 256 blocks x 512.

#define B_  2048
#define T_  512
#define V_  4
#define E_  64
#define H_  128
#define G3  384
#define G3P 392            // padded LDS stride (dwords): 392 % 32 = 8
#define SH  136            // h row stride (bf16 elems)
#define NB  8              // batch rows per block

#define LOG2E 1.4426950408889634f

typedef __attribute__((ext_vector_type(8))) short  short8;   // 8 bf16
typedef __attribute__((ext_vector_type(4))) float  float4v;
typedef __attribute__((ext_vector_type(2))) float  f32x2;    // -> v_pk_* f32

__device__ __forceinline__ short bf16s(float f) {            // RNE scalar (setup only)
  union { float ff; unsigned int u; } c; c.ff = f;
  return (short)((c.u + 0x7fffu + ((c.u >> 16) & 1u)) >> 16);
}

#define MFMA16(A, B, C) __builtin_amdgcn_mfma_f32_16x16x32_bf16((A), (B), (C), 0, 0, 0)

__global__ __launch_bounds__(512) void gru_kernel(
    const int* __restrict__ x, const float* __restrict__ emb,
    const float* __restrict__ W_ih, const float* __restrict__ W_hh,
    const float* __restrict__ b_ih, const float* __restrict__ b_hh,
    const float* __restrict__ W_fc, const float* __restrict__ b_fc,
    float* __restrict__ out) {
  __shared__ __align__(16) short hbuf[2][NB * SH];           // bf16 h, 8 rows
  __shared__ __align__(16) unsigned char xs[(T_ + 2) * NB];  // tokens [t][row], 2 pad rows
  __shared__ __align__(16) float tabS[V_ * G3P];             // gi table (pre-scaled, padded)
  __shared__ __align__(16) float hf[NB * H_];                // epilogue fp32 h

  const int tid  = threadIdx.x;
  const int w    = tid >> 6;        // wave 0..7
  const int lane = tid & 63;
  const int m    = lane & 15;       // B/C col: batch (m&7), replicated in cols 8-15
  const int q    = lane >> 4;       // quad
  const int mb   = m & 7;           // batch row
  const bool isHi = (m & 8) != 0;   // false: own elems {0,1}; true: own elems {2,3}
  const int g0   = blockIdx.x * NB;

  // ---- stage x -> xs[t][r] bytes (pre-masked); zero the 2 pad rows ----
  for (int i = tid; i < NB * T_; i += 512) {
    int r = i >> 9;                 // 0..7
    int t = i & (T_ - 1);
    xs[t * NB + r] = (unsigned char)(x[(g0 + r) * T_ + t] & 3);
  }
  if (tid < 2 * NB) xs[T_ * NB + tid] = 0;

  // ---- FUSED gi table: tab[v][g] = scale_g * (b_ih[g] + W_ih[g,:]@emb[v,:]
  //      (+ b_hh[g] for g<2H)); 3 entries/thread, W_ih+emb L2-cached ----
  for (int gid = tid; gid < V_ * G3; gid += 512) {
    int v = gid / G3;
    int g = gid - v * G3;
    float acc = b_ih[g];
    if (g < 2 * H_) acc += b_hh[g];
    const float4v* wr4 = (const float4v*)(W_ih + g * E_);   // 256B-aligned rows
    const float4v* er4 = (const float4v*)(emb + v * E_);
    float4v a4 = {0.f, 0.f, 0.f, 0.f};
#pragma unroll
    for (int e = 0; e < E_ / 4; ++e) a4 += wr4[e] * er4[e];
    acc += a4[0] + a4[1] + a4[2] + a4[3];
    tabS[v * G3P + g] = acc * ((g < 2 * H_) ? -LOG2E : 2.f * LOG2E);
  }

  // ---- zero both h buffers (h0 = 0) ----
  for (int i = tid; i < 2 * NB * SH; i += 512) hbuf[0][i] = 0;

  // ---- persistent A-fragments: W_hh tiles (pre-scaled), A[g=m][k=q*8+j] ----
  short8 wA[3][4];
#pragma unroll
  for (int s = 0; s < 3; ++s) {
    const float sc = (s < 2) ? -LOG2E : 2.f * LOG2E;
    const float* wrow = W_hh + (s * H_ + w * 16 + m) * H_;
#pragma unroll
    for (int ks = 0; ks < 4; ++ks) {
      const float* p = wrow + ks * 32 + q * 8;
      short8 f;
#pragma unroll
      for (int jj = 0; jj < 8; ++jj) f[jj] = bf16s(p[jj] * sc);
      wA[s][ks] = f;
    }
  }

  const int c0  = w * 16 + q * 4;          // C-row base (hdim) of this lane's accum
  const int c0r = c0 + (isHi ? 2 : 0);     // this lane's 2 assigned hdims
  float4v bhnC;                            // a2 chain C-init: b_hh_n * 2log2e
  {
    const float* p = b_hh + 2 * H_ + c0;
#pragma unroll
    for (int i = 0; i < 4; ++i) bhnC[i] = p[i] * 2.f * LOG2E;
  }
  f32x2 hA = {0.f, 0.f};            // this lane's 2 h values (hdim c0r+{0,1}, batch mb)

  __syncthreads();

  // ---- prologue: gi(0) into set A; token byte of t=1 ----
  float4v gAR, gAZ, gBR, gBZ;
  f32x2 gAN, gBN;
  int vb;
  {
    int v0 = xs[mb];
    const float* tb = &tabS[v0 * G3P + c0];
    gAR = *(const float4v*)(tb);
    gAZ = *(const float4v*)(tb + H_);
    gAN = *(const f32x2*)(&tabS[v0 * G3P + 2 * H_ + c0r]);
    vb  = xs[NB + mb];
  }

  const f32x2 one2 = {1.f, 1.f};

  // own-element select: lanes m<8 take elems {0,1}, lanes m>=8 take {2,3}.
  auto sel = [&](const float4v& xv) -> f32x2 {
    f32x2 r;
    r.x = isHi ? xv[2] : xv[0];
    r.y = isHi ? xv[3] : xv[1];
    return r;
  };

  auto step = [&](int FROM, int TO, int t,
                  float4v& guR, float4v& guZ, f32x2& guN,       // gi used this step
                  float4v& glR, float4v& glZ, f32x2& glN) {     // gi loaded for next
    // h fragments — read-side replication: col m carries batch m&7.
    const short* rbp = &hbuf[FROM][mb * SH + q * 8];
    short8 h0 = *(const short8*)(rbp);
    short8 h1 = *(const short8*)(rbp + 32);
    short8 h2 = *(const short8*)(rbp + 64);
    short8 h3 = *(const short8*)(rbp + 96);

    // ---- next-step gi: ds_reads issued EARLY, latency hides under MFMAs ----
    int vb2 = xs[(t + 2) * NB + mb];
    const float* tbn = &tabS[vb * G3P + c0];
    glR = *(const float4v*)(tbn);
    glZ = *(const float4v*)(tbn + H_);
    glN = *(const f32x2*)(tbn + 2 * H_ + (isHi ? 2 : 0));
    vb = vb2;

    // ---- all 12 MFMAs up front; a0 (r) leads, a2, a1 (z) last ----
    float4v a0 = MFMA16(wA[0][0], h0, guR);
    a0 = MFMA16(wA[0][1], h1, a0);
    a0 = MFMA16(wA[0][2], h2, a0);
    a0 = MFMA16(wA[0][3], h3, a0);
    float4v a2 = MFMA16(wA[2][0], h0, bhnC);
    a2 = MFMA16(wA[2][1], h1, a2);
    a2 = MFMA16(wA[2][2], h2, a2);
    a2 = MFMA16(wA[2][3], h3, a2);
    float4v a1 = MFMA16(wA[1][0], h0, guZ);
    a1 = MFMA16(wA[1][1], h1, a1);
    a1 = MFMA16(wA[1][2], h2, a1);
    a1 = MFMA16(wA[1][3], h3, a1);

    // ---- own 2 elems; r = rcp(1+Er) scalar trans under the queue drain ----
    f32x2 a0e = sel(a0);
    f32x2 rr;
    rr.x = __builtin_amdgcn_rcpf(1.f + __builtin_amdgcn_exp2f(a0e.x));
    rr.y = __builtin_amdgcn_rcpf(1.f + __builtin_amdgcn_exp2f(a0e.y));
    f32x2 a2e = sel(a2);
    f32x2 a1e = sel(a1);

    // ---- packed fused tail: h' = [e2n(Ez+h)+(h-Ez)] * rcp[(e2n+1)(1+Ez)] ----
    f32x2 np = rr * a2e + guN;                     // v_pk_fma_f32
    f32x2 e  = {__builtin_amdgcn_exp2f(np.x), __builtin_amdgcn_exp2f(np.y)};
    f32x2 Ez = {__builtin_amdgcn_exp2f(a1e.x), __builtin_amdgcn_exp2f(a1e.y)};
    f32x2 num = e * (Ez + hA) + (hA - Ez);         // pk_add, pk_fma, pk_add(neg)
    f32x2 den = (e + one2) * (one2 + Ez);          // pk_add x2, pk_mul
    f32x2 rc  = {__builtin_amdgcn_rcpf(den.x), __builtin_amdgcn_rcpf(den.y)};
    hA = num * rc;                                 // pk_mul
    unsigned int pk0;
    asm("v_cvt_pk_bf16_f32 %0, %1, %2" : "=v"(pk0) : "v"(hA.x), "v"(hA.y));
    *(unsigned int*)(&hbuf[TO][mb * SH + c0r]) = pk0;
    __syncthreads();
  };

  for (int t = 0; t < T_; t += 2) {
    step(0, 1, t,     gAR, gAZ, gAN, gBR, gBZ, gBN);
    step(1, 0, t + 1, gBR, gBZ, gBN, gAR, gAZ, gAN);
  }

  // ---- epilogue: logits = hT @ W_fc^T + b_fc ----
  hf[mb * H_ + c0r + 0] = hA.x;
  hf[mb * H_ + c0r + 1] = hA.y;
  __syncthreads();

  if (tid < NB * V_) {
    int row = tid >> 2, vo = tid & 3;
    float s = b_fc[vo];
    const float* wv = W_fc + vo * H_;
    const float* hr = &hf[row * H_];
#pragma unroll 4
    for (int k = 0; k < H_; k += 4)
      s += hr[k] * wv[k] + hr[k + 1] * wv[k + 1]
         + hr[k + 2] * wv[k + 2] + hr[k + 3] * wv[k + 3];
    out[(g0 + row) * V_ + vo] = s;
  }
}

extern "C" void kernel_launch(void* const* d_in, const int* in_sizes, int n_in,
                              void* d_out, int out_size, void* d_ws, size_t ws_size,
                              hipStream_t stream) {
  const int*   x    = (const int*)d_in[0];
  const float* emb  = (const float*)d_in[1];
  const float* W_ih = (const float*)d_in[2];
  const float* W_hh = (const float*)d_in[3];
  const float* b_ih = (const float*)d_in[4];
  const float* b_hh = (const float*)d_in[5];
  const float* W_fc = (const float*)d_in[6];
  const float* b_fc = (const float*)d_in[7];
  float* out   = (float*)d_out;
  (void)d_ws; (void)ws_size;

  gru_kernel<<<B_ / NB, 512, 0, stream>>>(x, emb, W_ih, W_hh, b_ih, b_hh,
                                          W_fc, b_fc, out);
}

// Round 9
// 268.312 us; speedup vs baseline: 1.0425x; 1.0425x over previous
//
#include <hip/hip_runtime.h>
#include <hip/hip_bf16.h>

// GRU policy: B=2048, T=512, V=4, E=64, H=128.
// R22 = R21 single-launch fusion + FIXED SETUP LOAD GRAPH. R21 post-mortem:
// fixed harness overhead = 22.5us (kernel-count-independent, unreachable);
// two-kernel extra cost was only ~5.5us; R21's fused table setup cost
// +12.6us because 48 dependency-chained loads/thread ran with zero resident
// TLP at block start. R22: ONE W_ih row per thread (threads 0..383; all 4
// token-values share the row) -> 16 INDEPENDENT float4 loads + 64 uniform
// emb loads issued in one burst, hidden under wA staging. Est setup <1us.
// Main loop: EXACTLY R20 (244.6us dispatch, verified best; step at floor:
// MFMA 12/wave forced by B/CU, trans 5/elem algebraic floor, LDS ops
// non-binding (R19), overlap 0-for-7, 2blk/CU 4.2x worse (R17)).
// Ledger: R14 pad WIN; R15 DPP FAIL; R16 occupancy WIN; R17 2blk FAIL;
// R18 splitK FAIL; R19 gi-reg FAIL; R20 reassembly WIN; R21 fusion net FAIL
// (setup latency). Pre-commit: harness >= 272.6 => revert to R20, floor.
// Per wave/step: 12 MFMA, 4 ds_read_b128(h) + 2 b128 + 1 b64 (gi) + 1 u8
// + 1 ds_write_b32, 10 trans, ~40 VALU. 1 barrier/step. 256 blocks x 512.

#define B_  2048
#define T_  512
#define V_  4
#define E_  64
#define H_  128
#define G3  384
#define G3P 392            // padded LDS stride (dwords): 392 % 32 = 8
#define SH  136            // h row stride (bf16 elems)
#define NB  8              // batch rows per block

#define LOG2E 1.4426950408889634f

typedef __attribute__((ext_vector_type(8))) short  short8;   // 8 bf16
typedef __attribute__((ext_vector_type(4))) float  float4v;
typedef __attribute__((ext_vector_type(2))) float  f32x2;    // -> v_pk_* f32

__device__ __forceinline__ short bf16s(float f) {            // RNE scalar (setup only)
  union { float ff; unsigned int u; } c; c.ff = f;
  return (short)((c.u + 0x7fffu + ((c.u >> 16) & 1u)) >> 16);
}

#define MFMA16(A, B, C) __builtin_amdgcn_mfma_f32_16x16x32_bf16((A), (B), (C), 0, 0, 0)

__global__ __launch_bounds__(512) void gru_kernel(
    const int* __restrict__ x, const float* __restrict__ emb,
    const float* __restrict__ W_ih, const float* __restrict__ W_hh,
    const float* __restrict__ b_ih, const float* __restrict__ b_hh,
    const float* __restrict__ W_fc, const float* __restrict__ b_fc,
    float* __restrict__ out) {
  __shared__ __align__(16) short hbuf[2][NB * SH];           // bf16 h, 8 rows
  __shared__ __align__(16) unsigned char xs[(T_ + 2) * NB];  // tokens [t][row], 2 pad rows
  __shared__ __align__(16) float tabS[V_ * G3P];             // gi table (pre-scaled, padded)
  __shared__ __align__(16) float hf[NB * H_];                // epilogue fp32 h

  const int tid  = threadIdx.x;
  const int w    = tid >> 6;        // wave 0..7
  const int lane = tid & 63;
  const int m    = lane & 15;       // B/C col: batch (m&7), replicated in cols 8-15
  const int q    = lane >> 4;       // quad
  const int mb   = m & 7;           // batch row
  const bool isHi = (m & 8) != 0;   // false: own elems {0,1}; true: own elems {2,3}
  const int g0   = blockIdx.x * NB;

  // ---- FUSED gi table, one W_ih row per thread (threads 0..383):
  //      tab[v][g] = sc_g * (b_ih[g] (+b_hh[g], g<2H) + W_ih[g,:]@emb[v,:])
  //      16 independent W_ih float4 loads + uniform emb loads, one burst ----
  if (tid < G3) {
    const int g = tid;
    float bias = b_ih[g];
    if (g < 2 * H_) bias += b_hh[g];
    const float sc = (g < 2 * H_) ? -LOG2E : 2.f * LOG2E;
    const float4v* wr4 = (const float4v*)(W_ih + g * E_);    // 256B-aligned row
    const float4v* e0 = (const float4v*)(emb);
    const float4v* e1 = (const float4v*)(emb + E_);
    const float4v* e2 = (const float4v*)(emb + 2 * E_);
    const float4v* e3 = (const float4v*)(emb + 3 * E_);
    float4v a0 = {0.f, 0.f, 0.f, 0.f}, a1 = a0, a2 = a0, a3 = a0;
#pragma unroll
    for (int e = 0; e < E_ / 4; ++e) {
      float4v wv = wr4[e];
      a0 += wv * e0[e];
      a1 += wv * e1[e];
      a2 += wv * e2[e];
      a3 += wv * e3[e];
    }
    tabS[0 * G3P + g] = (bias + a0[0] + a0[1] + a0[2] + a0[3]) * sc;
    tabS[1 * G3P + g] = (bias + a1[0] + a1[1] + a1[2] + a1[3]) * sc;
    tabS[2 * G3P + g] = (bias + a2[0] + a2[1] + a2[2] + a2[3]) * sc;
    tabS[3 * G3P + g] = (bias + a3[0] + a3[1] + a3[2] + a3[3]) * sc;
  }

  // ---- stage x -> xs[t][r] bytes (pre-masked); zero the 2 pad rows ----
  for (int i = tid; i < NB * T_; i += 512) {
    int r = i >> 9;                 // 0..7
    int t = i & (T_ - 1);
    xs[t * NB + r] = (unsigned char)(x[(g0 + r) * T_ + t] & 3);
  }
  if (tid < 2 * NB) xs[T_ * NB + tid] = 0;

  // ---- zero both h buffers (h0 = 0) ----
  for (int i = tid; i < 2 * NB * SH; i += 512) hbuf[0][i] = 0;

  // ---- persistent A-fragments: W_hh tiles (pre-scaled), A[g=m][k=q*8+j] ----
  short8 wA[3][4];
#pragma unroll
  for (int s = 0; s < 3; ++s) {
    const float sc = (s < 2) ? -LOG2E : 2.f * LOG2E;
    const float* wrow = W_hh + (s * H_ + w * 16 + m) * H_;
#pragma unroll
    for (int ks = 0; ks < 4; ++ks) {
      const float* p = wrow + ks * 32 + q * 8;
      short8 f;
#pragma unroll
      for (int jj = 0; jj < 8; ++jj) f[jj] = bf16s(p[jj] * sc);
      wA[s][ks] = f;
    }
  }

  const int c0  = w * 16 + q * 4;          // C-row base (hdim) of this lane's accum
  const int c0r = c0 + (isHi ? 2 : 0);     // this lane's 2 assigned hdims
  float4v bhnC;                            // a2 chain C-init: b_hh_n * 2log2e
  {
    const float* p = b_hh + 2 * H_ + c0;
#pragma unroll
    for (int i = 0; i < 4; ++i) bhnC[i] = p[i] * 2.f * LOG2E;
  }
  f32x2 hA = {0.f, 0.f};            // this lane's 2 h values (hdim c0r+{0,1}, batch mb)

  __syncthreads();

  // ---- prologue: gi(0) into set A; token byte of t=1 ----
  float4v gAR, gAZ, gBR, gBZ;
  f32x2 gAN, gBN;
  int vb;
  {
    int v0 = xs[mb];
    const float* tb = &tabS[v0 * G3P + c0];
    gAR = *(const float4v*)(tb);
    gAZ = *(const float4v*)(tb + H_);
    gAN = *(const f32x2*)(&tabS[v0 * G3P + 2 * H_ + c0r]);
    vb  = xs[NB + mb];
  }

  const f32x2 one2 = {1.f, 1.f};

  // own-element select: lanes m<8 take elems {0,1}, lanes m>=8 take {2,3}.
  auto sel = [&](const float4v& xv) -> f32x2 {
    f32x2 r;
    r.x = isHi ? xv[2] : xv[0];
    r.y = isHi ? xv[3] : xv[1];
    return r;
  };

  auto step = [&](int FROM, int TO, int t,
                  float4v& guR, float4v& guZ, f32x2& guN,       // gi used this step
                  float4v& glR, float4v& glZ, f32x2& glN) {     // gi loaded for next
    // h fragments — read-side replication: col m carries batch m&7.
    const short* rbp = &hbuf[FROM][mb * SH + q * 8];
    short8 h0 = *(const short8*)(rbp);
    short8 h1 = *(const short8*)(rbp + 32);
    short8 h2 = *(const short8*)(rbp + 64);
    short8 h3 = *(const short8*)(rbp + 96);

    // ---- next-step gi: ds_reads issued EARLY, latency hides under MFMAs ----
    int vb2 = xs[(t + 2) * NB + mb];
    const float* tbn = &tabS[vb * G3P + c0];
    glR = *(const float4v*)(tbn);
    glZ = *(const float4v*)(tbn + H_);
    glN = *(const f32x2*)(tbn + 2 * H_ + (isHi ? 2 : 0));
    vb = vb2;

    // ---- all 12 MFMAs up front; a0 (r) leads, a2, a1 (z) last ----
    float4v a0 = MFMA16(wA[0][0], h0, guR);
    a0 = MFMA16(wA[0][1], h1, a0);
    a0 = MFMA16(wA[0][2], h2, a0);
    a0 = MFMA16(wA[0][3], h3, a0);
    float4v a2 = MFMA16(wA[2][0], h0, bhnC);
    a2 = MFMA16(wA[2][1], h1, a2);
    a2 = MFMA16(wA[2][2], h2, a2);
    a2 = MFMA16(wA[2][3], h3, a2);
    float4v a1 = MFMA16(wA[1][0], h0, guZ);
    a1 = MFMA16(wA[1][1], h1, a1);
    a1 = MFMA16(wA[1][2], h2, a1);
    a1 = MFMA16(wA[1][3], h3, a1);

    // ---- own 2 elems; r = rcp(1+Er) scalar trans under the queue drain ----
    f32x2 a0e = sel(a0);
    f32x2 rr;
    rr.x = __builtin_amdgcn_rcpf(1.f + __builtin_amdgcn_exp2f(a0e.x));
    rr.y = __builtin_amdgcn_rcpf(1.f + __builtin_amdgcn_exp2f(a0e.y));
    f32x2 a2e = sel(a2);
    f32x2 a1e = sel(a1);

    // ---- packed fused tail: h' = [e2n(Ez+h)+(h-Ez)] * rcp[(e2n+1)(1+Ez)] ----
    f32x2 np = rr * a2e + guN;                     // v_pk_fma_f32
    f32x2 e  = {__builtin_amdgcn_exp2f(np.x), __builtin_amdgcn_exp2f(np.y)};
    f32x2 Ez = {__builtin_amdgcn_exp2f(a1e.x), __builtin_amdgcn_exp2f(a1e.y)};
    f32x2 num = e * (Ez + hA) + (hA - Ez);         // pk_add, pk_fma, pk_add(neg)
    f32x2 den = (e + one2) * (one2 + Ez);          // pk_add x2, pk_mul
    f32x2 rc  = {__builtin_amdgcn_rcpf(den.x), __builtin_amdgcn_rcpf(den.y)};
    hA = num * rc;                                 // pk_mul
    unsigned int pk0;
    asm("v_cvt_pk_bf16_f32 %0, %1, %2" : "=v"(pk0) : "v"(hA.x), "v"(hA.y));
    *(unsigned int*)(&hbuf[TO][mb * SH + c0r]) = pk0;
    __syncthreads();
  };

  for (int t = 0; t < T_; t += 2) {
    step(0, 1, t,     gAR, gAZ, gAN, gBR, gBZ, gBN);
    step(1, 0, t + 1, gBR, gBZ, gBN, gAR, gAZ, gAN);
  }

  // ---- epilogue: logits = hT @ W_fc^T + b_fc ----
  hf[mb * H_ + c0r + 0] = hA.x;
  hf[mb * H_ + c0r + 1] = hA.y;
  __syncthreads();

  if (tid < NB * V_) {
    int row = tid >> 2, vo = tid & 3;
    float s = b_fc[vo];
    const float* wv = W_fc + vo * H_;
    const float* hr = &hf[row * H_];
#pragma unroll 4
    for (int k = 0; k < H_; k += 4)
      s += hr[k] * wv[k] + hr[k + 1] * wv[k + 1]
         + hr[k + 2] * wv[k + 2] + hr[k + 3] * wv[k + 3];
    out[(g0 + row) * V_ + vo] = s;
  }
}

extern "C" void kernel_launch(void* const* d_in, const int* in_sizes, int n_in,
                              void* d_out, int out_size, void* d_ws, size_t ws_size,
                              hipStream_t stream) {
  const int*   x    = (const int*)d_in[0];
  const float* emb  = (const float*)d_in[1];
  const float* W_ih = (const float*)d_in[2];
  const float* W_hh = (const float*)d_in[3];
  const float* b_ih = (const float*)d_in[4];
  const float* b_hh = (const float*)d_in[5];
  const float* W_fc = (const float*)d_in[6];
  const float* b_fc = (const float*)d_in[7];
  float* out   = (float*)d_out;
  (void)d_ws; (void)ws_size;

  gru_kernel<<<B_ / NB, 512, 0, stream>>>(x, emb, W_ih, W_hh, b_ih, b_hh,
                                          W_fc, b_fc, out);
}